// Round 3
// baseline (992.797 us; speedup 1.0000x reference)
//
#include <hip/hip_runtime.h>
#include <hip/hip_fp16.h>
#include <math.h>

#define B_ 32
#define N_ 1024
#define E_ 2048
#define DD 11   // d = D + Hd = 3 + 8
#define HD 8
#define RTOT ((size_t)B_ * N_ * E_)   // 67,108,864 per R array

// ---------------- input network: H = [tanh(X@Wi+bi), X] ----------------
__global__ void k_input(const float* __restrict__ X, const float* __restrict__ Wi,
                        const float* __restrict__ bi, float* __restrict__ H) {
    int idx = blockIdx.x * 256 + threadIdx.x;
    if (idx >= B_ * N_) return;
    float x0 = X[idx * 3 + 0], x1 = X[idx * 3 + 1], x2 = X[idx * 3 + 2];
    float* h = H + (size_t)idx * DD;
    #pragma unroll
    for (int j = 0; j < HD; j++)
        h[j] = tanhf(x0 * Wi[0 * HD + j] + x1 * Wi[1 * HD + j] + x2 * Wi[2 * HD + j] + bi[j]);
    h[8] = x0; h[9] = x1; h[10] = x2;
}

// ---------------- Ri/Ro f32 -> fp16 copies (once per launch) ----------------
__global__ void k_convert(const float* __restrict__ Ri, const float* __restrict__ Ro,
                          __half* __restrict__ Rih, __half* __restrict__ Roh) {
    size_t i0 = ((size_t)blockIdx.x * 256 + threadIdx.x) * 8;
    size_t stride = (size_t)gridDim.x * 256 * 8;
    for (size_t i = i0; i < RTOT; i += stride) {
        float4 a0 = *(const float4*)(Ri + i);
        float4 a1 = *(const float4*)(Ri + i + 4);
        float4 b0 = *(const float4*)(Ro + i);
        float4 b1 = *(const float4*)(Ro + i + 4);
        uint4 ua, ub;
        *reinterpret_cast<__half2*>(&ua.x) = __floats2half2_rn(a0.x, a0.y);
        *reinterpret_cast<__half2*>(&ua.y) = __floats2half2_rn(a0.z, a0.w);
        *reinterpret_cast<__half2*>(&ua.z) = __floats2half2_rn(a1.x, a1.y);
        *reinterpret_cast<__half2*>(&ua.w) = __floats2half2_rn(a1.z, a1.w);
        *reinterpret_cast<__half2*>(&ub.x) = __floats2half2_rn(b0.x, b0.y);
        *reinterpret_cast<__half2*>(&ub.y) = __floats2half2_rn(b0.z, b0.w);
        *reinterpret_cast<__half2*>(&ub.z) = __floats2half2_rn(b1.x, b1.y);
        *reinterpret_cast<__half2*>(&ub.w) = __floats2half2_rn(b1.z, b1.w);
        *(uint4*)(Rih + i) = ua;
        *(uint4*)(Roh + i) = ub;
    }
}

// ---------------- shared edge MLP ----------------
__device__ inline float edge_mlp(const float* ao, const float* ai,
        const float* __restrict__ We1, const float* __restrict__ be1,
        const float* __restrict__ We2, const float* __restrict__ be2) {
    float h[HD];
    #pragma unroll
    for (int j = 0; j < HD; j++) {
        float acc = be1[j];
        #pragma unroll
        for (int d = 0; d < DD; d++) acc = fmaf(ao[d], We1[d * HD + j], acc);
        #pragma unroll
        for (int d = 0; d < DD; d++) acc = fmaf(ai[d], We1[(DD + d) * HD + j], acc);
        h[j] = tanhf(acc);
    }
    float sacc = be2[0];
    #pragma unroll
    for (int j = 0; j < HD; j++) sacc = fmaf(h[j], We2[j], sacc);
    return 1.f / (1.f + expf(-sacc));
}

// ---------------- fused gather + edge MLP, fp16 R, 2 edges/lane ----------------
// grid = B * (E/128); block 256 (4 waves, wave w sums n in [w*256,(w+1)*256)).
__global__ __launch_bounds__(256) void k_edge_h(
        const __half* __restrict__ Ri, const __half* __restrict__ Ro,
        const float* __restrict__ H,
        const float* __restrict__ We1, const float* __restrict__ be1,
        const float* __restrict__ We2, const float* __restrict__ be2,
        float* __restrict__ wbo, float* __restrict__ wbi,
        float* __restrict__ out, int final_) {
    __shared__ float red[3][64][4 * DD];   // 33.8 KB
    int bid = blockIdx.x;
    int eb = (bid & 15) << 7;          // 16 tiles of 128 edges
    int b  = bid >> 4;
    int tid = threadIdx.x;
    int w = tid >> 6, lane = tid & 63;
    int e0 = eb + (lane << 1);
    int n0 = w << 8;

    float ao0[DD], ao1[DD], ai0[DD], ai1[DD];
    #pragma unroll
    for (int d = 0; d < DD; d++) { ao0[d]=0.f; ao1[d]=0.f; ai0[d]=0.f; ai1[d]=0.f; }

    const __half2* ri2 = (const __half2*)(Ri + ((size_t)b * N_ + n0) * E_ + e0);
    const __half2* ro2 = (const __half2*)(Ro + ((size_t)b * N_ + n0) * E_ + e0);
    int hbase = __builtin_amdgcn_readfirstlane((b * N_ + n0) * DD);
    const float* hp = H + hbase;       // wave-uniform -> scalar loads

    #pragma unroll 4
    for (int n = 0; n < 256; n++) {
        float2 vi = __half22float2(ri2[(size_t)n * (E_ / 2)]);
        float2 vo = __half22float2(ro2[(size_t)n * (E_ / 2)]);
        #pragma unroll
        for (int d = 0; d < DD; d++) {
            float hv = hp[n * DD + d];
            ao0[d] = fmaf(vo.x, hv, ao0[d]);
            ao1[d] = fmaf(vo.y, hv, ao1[d]);
            ai0[d] = fmaf(vi.x, hv, ai0[d]);
            ai1[d] = fmaf(vi.y, hv, ai1[d]);
        }
    }
    if (w) {
        #pragma unroll
        for (int d = 0; d < DD; d++) {
            red[w-1][lane][d]          = ao0[d];
            red[w-1][lane][DD + d]     = ao1[d];
            red[w-1][lane][2*DD + d]   = ai0[d];
            red[w-1][lane][3*DD + d]   = ai1[d];
        }
    }
    __syncthreads();
    if (w == 0) {
        #pragma unroll
        for (int ww = 0; ww < 3; ww++)
            #pragma unroll
            for (int d = 0; d < DD; d++) {
                ao0[d] += red[ww][lane][d];
                ao1[d] += red[ww][lane][DD + d];
                ai0[d] += red[ww][lane][2*DD + d];
                ai1[d] += red[ww][lane][3*DD + d];
            }
        float ew0 = edge_mlp(ao0, ai0, We1, be1, We2, be2);
        float ew1 = edge_mlp(ao1, ai1, We1, be1, We2, be2);
        size_t idx = (size_t)b * E_ + e0;
        if (final_) {
            out[idx] = ew0; out[idx + 1] = ew1;
        } else {
            #pragma unroll
            for (int d = 0; d < DD; d++) {
                wbo[idx * DD + d]        = ew0 * ao0[d];
                wbo[(idx + 1) * DD + d]  = ew1 * ao1[d];
                wbi[idx * DD + d]        = ew0 * ai0[d];
                wbi[(idx + 1) * DD + d]  = ew1 * ai1[d];
            }
        }
    }
}

// ---------------- fused gather + edge MLP, f32 fallback ----------------
__global__ __launch_bounds__(256) void k_edge_f(
        const float* __restrict__ Ri, const float* __restrict__ Ro,
        const float* __restrict__ H,
        const float* __restrict__ We1, const float* __restrict__ be1,
        const float* __restrict__ We2, const float* __restrict__ be2,
        float* __restrict__ wbo, float* __restrict__ wbi,
        float* __restrict__ out, int final_) {
    __shared__ float red[3][64][2 * DD];
    int bid = blockIdx.x;
    int eb = (bid & 31) << 6;
    int b  = bid >> 5;
    int tid = threadIdx.x;
    int w = tid >> 6, lane = tid & 63;
    int e = eb + lane;
    int n0 = w << 8;

    float ao[DD], ai[DD];
    #pragma unroll
    for (int d = 0; d < DD; d++) { ao[d] = 0.f; ai[d] = 0.f; }

    const float* ri = Ri + ((size_t)b * N_ + n0) * E_ + e;
    const float* ro = Ro + ((size_t)b * N_ + n0) * E_ + e;
    int hbase = __builtin_amdgcn_readfirstlane((b * N_ + n0) * DD);
    const float* hp = H + hbase;

    #pragma unroll 4
    for (int n = 0; n < 256; n++) {
        float vi = ri[(size_t)n * E_];
        float vo = ro[(size_t)n * E_];
        #pragma unroll
        for (int d = 0; d < DD; d++) {
            float hv = hp[n * DD + d];
            ao[d] = fmaf(vo, hv, ao[d]);
            ai[d] = fmaf(vi, hv, ai[d]);
        }
    }
    if (w) {
        #pragma unroll
        for (int d = 0; d < DD; d++) {
            red[w - 1][lane][d]      = ao[d];
            red[w - 1][lane][DD + d] = ai[d];
        }
    }
    __syncthreads();
    if (w == 0) {
        #pragma unroll
        for (int ww = 0; ww < 3; ww++)
            #pragma unroll
            for (int d = 0; d < DD; d++) {
                ao[d] += red[ww][lane][d];
                ai[d] += red[ww][lane][DD + d];
            }
        float ew = edge_mlp(ao, ai, We1, be1, We2, be2);
        size_t idx = (size_t)b * E_ + e;
        if (final_) {
            out[idx] = ew;
        } else {
            #pragma unroll
            for (int d = 0; d < DD; d++) {
                wbo[idx * DD + d] = ew * ao[d];
                wbi[idx * DD + d] = ew * ai[d];
            }
        }
    }
}

// ---------------- scatter (templated on R dtype) ----------------
// mi[b,n,:] = sum_e Ri[b,n,e] wbo[b,e,:]; mo likewise (Ro, wbi).
// LDS tiles [256][19]: odd stride -> 2-way (free) bank aliasing on column reads.
template<typename RT>
__global__ __launch_bounds__(256) void k_scatter_t(const RT* __restrict__ Ri,
        const RT* __restrict__ Ro, const float* __restrict__ wbo,
        const float* __restrict__ wbi, float* __restrict__ part, int NS) {
    __shared__ float TA[256][19];   // 38.9 KB total -> 4 blocks/CU
    __shared__ float TB[256][19];
    int bid = blockIdx.x;
    int nt = bid & 3;
    int s  = (bid >> 2) % NS;
    int b  = bid / (4 * NS);
    int n0 = nt << 8;
    int eper = E_ / NS;
    int e0 = s * eper;
    int tid = threadIdx.x;

    float mi[DD], mo[DD];
    #pragma unroll
    for (int d = 0; d < DD; d++) { mi[d] = 0.f; mo[d] = 0.f; }

    constexpr bool IS_H = sizeof(RT) == 2;
    // f32: r=tid>>2 (rows r+64k, k<4), c4=(tid&3)*4, float4 loads
    // fp16: r=tid>>1 (rows r+128k, k<2), c8=(tid&1)*8, uint4 (8-half) loads
    int rF = tid >> 2, cF = (tid & 3) << 2;
    int rH = tid >> 1, cH = (tid & 1) << 3;

    const RT* bRi = Ri + ((size_t)b * N_ + n0) * E_ + e0;
    const RT* bRo = Ro + ((size_t)b * N_ + n0) * E_ + e0;

    float4 pa[4], pb[4];     // f32 staging
    uint4  qa[2], qb[2];     // fp16 staging

    auto LOADC = [&](int ec) {
        if constexpr (IS_H) {
            #pragma unroll
            for (int k = 0; k < 2; k++) {
                size_t off = (size_t)(rH + (k << 7)) * E_ + ec + cH;
                qa[k] = *(const uint4*)(bRi + off);
                qb[k] = *(const uint4*)(bRo + off);
            }
        } else {
            #pragma unroll
            for (int k = 0; k < 4; k++) {
                size_t off = (size_t)(rF + (k << 6)) * E_ + ec + cF;
                pa[k] = *(const float4*)((const float*)bRi + off);
                pb[k] = *(const float4*)((const float*)bRo + off);
            }
        }
    };
    auto WRITEC = [&]() {
        if constexpr (IS_H) {
            #pragma unroll
            for (int k = 0; k < 2; k++) {
                int row = rH + (k << 7);
                const __half2* ha = (const __half2*)&qa[k];
                const __half2* hb = (const __half2*)&qb[k];
                #pragma unroll
                for (int j = 0; j < 4; j++) {
                    float2 fa = __half22float2(ha[j]);
                    float2 fb = __half22float2(hb[j]);
                    TA[row][cH + 2*j]     = fa.x;
                    TA[row][cH + 2*j + 1] = fa.y;
                    TB[row][cH + 2*j]     = fb.x;
                    TB[row][cH + 2*j + 1] = fb.y;
                }
            }
        } else {
            #pragma unroll
            for (int k = 0; k < 4; k++) {
                int row = rF + (k << 6);
                TA[row][cF + 0] = pa[k].x; TA[row][cF + 1] = pa[k].y;
                TA[row][cF + 2] = pa[k].z; TA[row][cF + 3] = pa[k].w;
                TB[row][cF + 0] = pb[k].x; TB[row][cF + 1] = pb[k].y;
                TB[row][cF + 2] = pb[k].z; TB[row][cF + 3] = pb[k].w;
            }
        }
    };

    LOADC(0);
    WRITEC();
    __syncthreads();
    for (int ec = 0; ec < eper; ec += 16) {
        bool more = (ec + 16) < eper;
        if (more) LOADC(ec + 16);
        const float* wo = wbo + ((size_t)b * E_ + e0 + ec) * DD;  // block-uniform
        const float* wi = wbi + ((size_t)b * E_ + e0 + ec) * DD;
        #pragma unroll
        for (int j = 0; j < 16; j++) {
            float vA = TA[tid][j];
            float vB = TB[tid][j];
            #pragma unroll
            for (int d = 0; d < DD; d++) {
                mi[d] = fmaf(vA, wo[j * DD + d], mi[d]);
                mo[d] = fmaf(vB, wi[j * DD + d], mo[d]);
            }
        }
        if (more) {
            __syncthreads();
            WRITEC();
            __syncthreads();
        }
    }
    size_t bmi = ((size_t)(s * B_ + b)) * DD * N_ + n0 + tid;
    size_t bmo = ((size_t)((NS + s) * B_ + b)) * DD * N_ + n0 + tid;
    #pragma unroll
    for (int d = 0; d < DD; d++) {
        part[bmi + (size_t)d * N_] = mi[d];
        part[bmo + (size_t)d * N_] = mo[d];
    }
}

// ---------------- node finish: reduce partials, node MLP, H = [tanh(.), X] -------
__global__ void k_node_finish(const float* __restrict__ part,
        const float* __restrict__ Wn1, const float* __restrict__ bn1,
        const float* __restrict__ Wn2, const float* __restrict__ bn2,
        float* __restrict__ H, int NS) {
    int idx = blockIdx.x * 256 + threadIdx.x;
    if (idx >= B_ * N_) return;
    int b = idx / N_, n = idx % N_;

    float mi[DD], mo[DD];
    #pragma unroll
    for (int d = 0; d < DD; d++) { mi[d] = 0.f; mo[d] = 0.f; }
    for (int s = 0; s < NS; s++) {
        size_t pmi = ((size_t)(s * B_ + b)) * DD * N_ + n;
        size_t pmo = ((size_t)((NS + s) * B_ + b)) * DD * N_ + n;
        #pragma unroll
        for (int d = 0; d < DD; d++) {
            mi[d] += part[pmi + (size_t)d * N_];
            mo[d] += part[pmo + (size_t)d * N_];
        }
    }
    float* h = H + (size_t)idx * DD;
    float hold[DD];
    #pragma unroll
    for (int d = 0; d < DD; d++) hold[d] = h[d];

    float t1[HD];
    #pragma unroll
    for (int j = 0; j < HD; j++) {
        float acc = bn1[j];
        #pragma unroll
        for (int d = 0; d < DD; d++) acc = fmaf(mi[d],   Wn1[d * HD + j], acc);
        #pragma unroll
        for (int d = 0; d < DD; d++) acc = fmaf(mo[d],   Wn1[(DD + d) * HD + j], acc);
        #pragma unroll
        for (int d = 0; d < DD; d++) acc = fmaf(hold[d], Wn1[(2 * DD + d) * HD + j], acc);
        t1[j] = tanhf(acc);
    }
    #pragma unroll
    for (int j = 0; j < HD; j++) {
        float acc = bn2[j];
        #pragma unroll
        for (int k = 0; k < HD; k++) acc = fmaf(t1[k], Wn2[k * HD + j], acc);
        h[j] = tanhf(acc);
    }
}

extern "C" void kernel_launch(void* const* d_in, const int* in_sizes, int n_in,
                              void* d_out, int out_size, void* d_ws, size_t ws_size,
                              hipStream_t stream) {
    const float* X   = (const float*)d_in[0];
    const float* Ri  = (const float*)d_in[1];
    const float* Ro  = (const float*)d_in[2];
    const float* Wi  = (const float*)d_in[3];
    const float* bi  = (const float*)d_in[4];
    const float* We1 = (const float*)d_in[5];
    const float* be1 = (const float*)d_in[6];
    const float* We2 = (const float*)d_in[7];
    const float* be2 = (const float*)d_in[8];
    const float* Wn1 = (const float*)d_in[9];
    const float* bn1 = (const float*)d_in[10];
    const float* Wn2 = (const float*)d_in[11];
    const float* bn2 = (const float*)d_in[12];
    float* out = (float*)d_out;

    const size_t H_FL   = (size_t)B_ * N_ * DD;       // 360,448
    const size_t WB_FL  = (size_t)B_ * E_ * DD;       // 720,896
    auto spart_fl = [](int nss) { return 2ull * nss * B_ * DD * N_; };

    size_t need16B = 2ull * RTOT * 2 + (H_FL + 2 * WB_FL + spart_fl(8)) * 4;

    if (ws_size >= need16B) {
        // ---------------- fp16 path ----------------
        const int NSS = 8;
        char* p = (char*)d_ws;
        __half* Rih = (__half*)p;  p += RTOT * 2;
        __half* Roh = (__half*)p;  p += RTOT * 2;
        float* H    = (float*)p;   p += H_FL * 4;
        float* wbo  = (float*)p;   p += WB_FL * 4;
        float* wbi  = (float*)p;   p += WB_FL * 4;
        float* spart = (float*)p;

        k_convert<<<4096, 256, 0, stream>>>(Ri, Ro, Rih, Roh);
        k_input<<<(B_ * N_ + 255) / 256, 256, 0, stream>>>(X, Wi, bi, H);
        for (int it = 0; it < 3; it++) {
            k_edge_h<<<B_ * 16, 256, 0, stream>>>(Rih, Roh, H, We1, be1, We2, be2,
                                                  wbo, wbi, out, 0);
            k_scatter_t<__half><<<B_ * 4 * NSS, 256, 0, stream>>>(
                Rih, Roh, wbo, wbi, spart, NSS);
            k_node_finish<<<(B_ * N_ + 255) / 256, 256, 0, stream>>>(
                spart, Wn1, bn1, Wn2, bn2, H, NSS);
        }
        k_edge_h<<<B_ * 16, 256, 0, stream>>>(Rih, Roh, H, We1, be1, We2, be2,
                                              wbo, wbi, out, 1);
    } else {
        // ---------------- f32 fallback ----------------
        size_t fl = ws_size / sizeof(float);
        int NSS = 8;
        auto need = [&](int s) { return H_FL + 2 * WB_FL + spart_fl(s); };
        if (need(NSS) > fl) NSS = 4;
        if (need(NSS) > fl) NSS = 2;

        float* ws    = (float*)d_ws;
        float* H     = ws;  ws += H_FL;
        float* wbo   = ws;  ws += WB_FL;
        float* wbi   = ws;  ws += WB_FL;
        float* spart = ws;

        k_input<<<(B_ * N_ + 255) / 256, 256, 0, stream>>>(X, Wi, bi, H);
        for (int it = 0; it < 3; it++) {
            k_edge_f<<<B_ * 32, 256, 0, stream>>>(Ri, Ro, H, We1, be1, We2, be2,
                                                  wbo, wbi, out, 0);
            k_scatter_t<float><<<B_ * 4 * NSS, 256, 0, stream>>>(
                Ri, Ro, wbo, wbi, spart, NSS);
            k_node_finish<<<(B_ * N_ + 255) / 256, 256, 0, stream>>>(
                spart, Wn1, bn1, Wn2, bn2, H, NSS);
        }
        k_edge_f<<<B_ * 32, 256, 0, stream>>>(Ri, Ro, H, We1, be1, We2, be2,
                                              wbo, wbi, out, 1);
    }
}

// Round 4
// 779.809 us; speedup vs baseline: 1.2731x; 1.2731x over previous
//
#include <hip/hip_runtime.h>
#include <hip/hip_fp16.h>
#include <math.h>

#define B_ 32
#define N_ 1024
#define E_ 2048
#define DD 11   // d = D + Hd = 3 + 8
#define HD 8
#define RTOT ((size_t)B_ * N_ * E_)   // 67,108,864 per R array

// ---------------- input network: H = [tanh(X@Wi+bi), X] ----------------
__global__ void k_input(const float* __restrict__ X, const float* __restrict__ Wi,
                        const float* __restrict__ bi, float* __restrict__ H) {
    int idx = blockIdx.x * 256 + threadIdx.x;
    if (idx >= B_ * N_) return;
    float x0 = X[idx * 3 + 0], x1 = X[idx * 3 + 1], x2 = X[idx * 3 + 2];
    float* h = H + (size_t)idx * DD;
    #pragma unroll
    for (int j = 0; j < HD; j++)
        h[j] = tanhf(x0 * Wi[0 * HD + j] + x1 * Wi[1 * HD + j] + x2 * Wi[2 * HD + j] + bi[j]);
    h[8] = x0; h[9] = x1; h[10] = x2;
}

// ---------------- shared edge MLP ----------------
__device__ inline float edge_mlp(const float* ao, const float* ai,
        const float* __restrict__ We1, const float* __restrict__ be1,
        const float* __restrict__ We2, const float* __restrict__ be2) {
    float h[HD];
    #pragma unroll
    for (int j = 0; j < HD; j++) {
        float acc = be1[j];
        #pragma unroll
        for (int d = 0; d < DD; d++) acc = fmaf(ao[d], We1[d * HD + j], acc);
        #pragma unroll
        for (int d = 0; d < DD; d++) acc = fmaf(ai[d], We1[(DD + d) * HD + j], acc);
        h[j] = tanhf(acc);
    }
    float sacc = be2[0];
    #pragma unroll
    for (int j = 0; j < HD; j++) sacc = fmaf(h[j], We2[j], sacc);
    return 1.f / (1.f + expf(-sacc));
}

// ---------------- fused: transpose-convert f32->fp16T + iteration-0 edge ----------
// grid = B * (E/64); block 256 (4 waves). Per 64x64 f32 tile staged in LDS:
//  (a) gather-accumulate ao/ai (wave w owns 16 tile rows),
//  (b) write transposed fp16 RT[b][e][n] coalesced.
// Then cross-wave reduce + edge MLP -> wbo/wbi.
__global__ __launch_bounds__(256) void k_fused(
        const float* __restrict__ Ri, const float* __restrict__ Ro,
        const float* __restrict__ H,
        const float* __restrict__ We1, const float* __restrict__ be1,
        const float* __restrict__ We2, const float* __restrict__ be2,
        __half* __restrict__ RiT, __half* __restrict__ RoT,
        float* __restrict__ wbo, float* __restrict__ wbi) {
    __shared__ float tile[64][65];          // 16.6 KB, pitch 65: all phases conflict-free
    __shared__ float red[3][64][2 * DD];    // 16.9 KB
    int bid = blockIdx.x;
    int e0 = (bid & 31) << 6;               // 32 e-tiles of 64
    int b  = bid >> 5;
    int tid = threadIdx.x;
    int w = tid >> 6, lane = tid & 63;
    int lr = tid >> 4;                      // 0..15 (+16k)
    int lc = (tid & 15) << 2;               // 0,4,...,60
    int wbase = __builtin_amdgcn_readfirstlane(w << 4);
    const float* hp = H + (size_t)b * N_ * DD;

    float ai[DD], ao[DD];
    #pragma unroll
    for (int d = 0; d < DD; d++) { ai[d] = 0.f; ao[d] = 0.f; }

    auto process = [&](const float* __restrict__ Rg, __half* __restrict__ RT,
                       float (&acc)[DD]) {
        for (int nt = 0; nt < 16; nt++) {
            int nb = nt << 6;
            __syncthreads();                // protect tile from previous readers
            const float* src = Rg + ((size_t)(b * N_ + nb)) * E_ + e0;
            #pragma unroll
            for (int k = 0; k < 4; k++) {
                int r = lr + (k << 4);
                float4 v = *(const float4*)(src + (size_t)r * E_ + lc);
                tile[r][lc + 0] = v.x; tile[r][lc + 1] = v.y;
                tile[r][lc + 2] = v.z; tile[r][lc + 3] = v.w;
            }
            __syncthreads();
            // gather: wave w reads tile rows [wbase, wbase+16), H via s_loads
            #pragma unroll 4
            for (int j = 0; j < 16; j++) {
                int nl = wbase + j;
                float v = tile[nl][lane];
                #pragma unroll
                for (int d = 0; d < DD; d++)
                    acc[d] = fmaf(v, hp[(nb + nl) * DD + d], acc[d]);
            }
            // transposed fp16 write-out: row e = e0+re, cols n = nb+lc..+3
            #pragma unroll
            for (int k = 0; k < 4; k++) {
                int re = lr + (k << 4);
                float v0 = tile[lc + 0][re];
                float v1 = tile[lc + 1][re];
                float v2 = tile[lc + 2][re];
                float v3 = tile[lc + 3][re];
                __half2 h0 = __floats2half2_rn(v0, v1);
                __half2 h1 = __floats2half2_rn(v2, v3);
                uint2 u;
                u.x = *(unsigned*)&h0;
                u.y = *(unsigned*)&h1;
                *(uint2*)(RT + ((size_t)(b * E_ + e0 + re)) * N_ + nb + lc) = u;
            }
        }
    };
    process(Ri, RiT, ai);
    process(Ro, RoT, ao);

    if (w) {
        #pragma unroll
        for (int d = 0; d < DD; d++) {
            red[w - 1][lane][d]      = ao[d];
            red[w - 1][lane][DD + d] = ai[d];
        }
    }
    __syncthreads();
    if (w == 0) {
        #pragma unroll
        for (int ww = 0; ww < 3; ww++)
            #pragma unroll
            for (int d = 0; d < DD; d++) {
                ao[d] += red[ww][lane][d];
                ai[d] += red[ww][lane][DD + d];
            }
        float ew = edge_mlp(ao, ai, We1, be1, We2, be2);
        size_t idx = (size_t)b * E_ + e0 + lane;
        #pragma unroll
        for (int d = 0; d < DD; d++) {
            wbo[idx * DD + d] = ew * ao[d];
            wbi[idx * DD + d] = ew * ai[d];
        }
    }
}

// ---------------- fused gather + edge MLP, f32 (proven 5.6 TB/s) ----------------
__global__ __launch_bounds__(256) void k_edge_f(
        const float* __restrict__ Ri, const float* __restrict__ Ro,
        const float* __restrict__ H,
        const float* __restrict__ We1, const float* __restrict__ be1,
        const float* __restrict__ We2, const float* __restrict__ be2,
        float* __restrict__ wbo, float* __restrict__ wbi,
        float* __restrict__ out, int final_) {
    __shared__ float red[3][64][2 * DD];
    int bid = blockIdx.x;
    int eb = (bid & 31) << 6;
    int b  = bid >> 5;
    int tid = threadIdx.x;
    int w = tid >> 6, lane = tid & 63;
    int e = eb + lane;
    int n0 = w << 8;

    float ao[DD], ai[DD];
    #pragma unroll
    for (int d = 0; d < DD; d++) { ao[d] = 0.f; ai[d] = 0.f; }

    const float* ri = Ri + ((size_t)b * N_ + n0) * E_ + e;
    const float* ro = Ro + ((size_t)b * N_ + n0) * E_ + e;
    int hbase = __builtin_amdgcn_readfirstlane((b * N_ + n0) * DD);
    const float* hp = H + hbase;

    #pragma unroll 4
    for (int n = 0; n < 256; n++) {
        float vi = ri[(size_t)n * E_];
        float vo = ro[(size_t)n * E_];
        #pragma unroll
        for (int d = 0; d < DD; d++) {
            float hv = hp[n * DD + d];
            ao[d] = fmaf(vo, hv, ao[d]);
            ai[d] = fmaf(vi, hv, ai[d]);
        }
    }
    if (w) {
        #pragma unroll
        for (int d = 0; d < DD; d++) {
            red[w - 1][lane][d]      = ao[d];
            red[w - 1][lane][DD + d] = ai[d];
        }
    }
    __syncthreads();
    if (w == 0) {
        #pragma unroll
        for (int ww = 0; ww < 3; ww++)
            #pragma unroll
            for (int d = 0; d < DD; d++) {
                ao[d] += red[ww][lane][d];
                ai[d] += red[ww][lane][DD + d];
            }
        float ew = edge_mlp(ao, ai, We1, be1, We2, be2);
        size_t idx = (size_t)b * E_ + e;
        if (final_) {
            out[idx] = ew;
        } else {
            #pragma unroll
            for (int d = 0; d < DD; d++) {
                wbo[idx * DD + d] = ew * ao[d];
                wbi[idx * DD + d] = ew * ai[d];
            }
        }
    }
}

// ---------------- transposed scatter: coalesced in n, no LDS ----------------
// mi[b,n,:] = sum_e RiT[b,e,n] * wbo[b,e,:]; mo likewise (RoT, wbi).
// grid = B * 2(n-halves) * NS(e-slices); each lane owns 2 consecutive n.
__global__ __launch_bounds__(256) void k_scatter_T(
        const __half* __restrict__ RiT, const __half* __restrict__ RoT,
        const float* __restrict__ wbo, const float* __restrict__ wbi,
        float* __restrict__ part, int NS) {
    int bid = blockIdx.x;
    int nt = bid & 1;
    int s  = (bid >> 1) % NS;
    int b  = bid / (2 * NS);
    int n  = (nt << 9) + (threadIdx.x << 1);
    int eper = E_ / NS;
    int e0 = s * eper;

    const __half* pI = RiT + ((size_t)(b * E_ + e0)) * N_ + n;
    const __half* pO = RoT + ((size_t)(b * E_ + e0)) * N_ + n;
    const float* wo = wbo + ((size_t)(b * E_ + e0)) * DD;  // block-uniform -> s_load
    const float* wi = wbi + ((size_t)(b * E_ + e0)) * DD;

    float mi0[DD], mi1[DD], mo0[DD], mo1[DD];
    #pragma unroll
    for (int d = 0; d < DD; d++) { mi0[d]=0.f; mi1[d]=0.f; mo0[d]=0.f; mo1[d]=0.f; }

    #pragma unroll 4
    for (int e = 0; e < eper; e++) {
        float2 fI = __half22float2(*(const __half2*)(pI + (size_t)e * N_));
        float2 fO = __half22float2(*(const __half2*)(pO + (size_t)e * N_));
        #pragma unroll
        for (int d = 0; d < DD; d++) {
            float a = wo[e * DD + d];
            float c = wi[e * DD + d];
            mi0[d] = fmaf(fI.x, a, mi0[d]);
            mi1[d] = fmaf(fI.y, a, mi1[d]);
            mo0[d] = fmaf(fO.x, c, mo0[d]);
            mo1[d] = fmaf(fO.y, c, mo1[d]);
        }
    }
    size_t bmi = ((size_t)(s * B_ + b)) * DD * N_ + n;
    size_t bmo = ((size_t)((NS + s) * B_ + b)) * DD * N_ + n;
    #pragma unroll
    for (int d = 0; d < DD; d++) {
        *(float2*)&part[bmi + (size_t)d * N_] = make_float2(mi0[d], mi1[d]);
        *(float2*)&part[bmo + (size_t)d * N_] = make_float2(mo0[d], mo1[d]);
    }
}

// ---------------- f32 fallback scatter (LDS-staged, pad 19) ----------------
__global__ __launch_bounds__(256) void k_scatter_f(const float* __restrict__ Ri,
        const float* __restrict__ Ro, const float* __restrict__ wbo,
        const float* __restrict__ wbi, float* __restrict__ part, int NS) {
    __shared__ float TA[256][19];
    __shared__ float TB[256][19];
    int bid = blockIdx.x;
    int nt = bid & 3;
    int s  = (bid >> 2) % NS;
    int b  = bid / (4 * NS);
    int n0 = nt << 8;
    int eper = E_ / NS;
    int e0 = s * eper;
    int tid = threadIdx.x;
    int rF = tid >> 2, cF = (tid & 3) << 2;

    const float* bRi = Ri + ((size_t)b * N_ + n0) * E_ + e0;
    const float* bRo = Ro + ((size_t)b * N_ + n0) * E_ + e0;

    float mi[DD], mo[DD];
    #pragma unroll
    for (int d = 0; d < DD; d++) { mi[d] = 0.f; mo[d] = 0.f; }

    float4 pa[4], pb[4];
    auto LOADC = [&](int ec) {
        #pragma unroll
        for (int k = 0; k < 4; k++) {
            size_t off = (size_t)(rF + (k << 6)) * E_ + ec + cF;
            pa[k] = *(const float4*)(bRi + off);
            pb[k] = *(const float4*)(bRo + off);
        }
    };
    auto WRITEC = [&]() {
        #pragma unroll
        for (int k = 0; k < 4; k++) {
            int row = rF + (k << 6);
            TA[row][cF + 0] = pa[k].x; TA[row][cF + 1] = pa[k].y;
            TA[row][cF + 2] = pa[k].z; TA[row][cF + 3] = pa[k].w;
            TB[row][cF + 0] = pb[k].x; TB[row][cF + 1] = pb[k].y;
            TB[row][cF + 2] = pb[k].z; TB[row][cF + 3] = pb[k].w;
        }
    };

    LOADC(0);
    WRITEC();
    __syncthreads();
    for (int ec = 0; ec < eper; ec += 16) {
        bool more = (ec + 16) < eper;
        if (more) LOADC(ec + 16);
        const float* wo = wbo + ((size_t)b * E_ + e0 + ec) * DD;
        const float* wi = wbi + ((size_t)b * E_ + e0 + ec) * DD;
        #pragma unroll
        for (int j = 0; j < 16; j++) {
            float vA = TA[tid][j];
            float vB = TB[tid][j];
            #pragma unroll
            for (int d = 0; d < DD; d++) {
                mi[d] = fmaf(vA, wo[j * DD + d], mi[d]);
                mo[d] = fmaf(vB, wi[j * DD + d], mo[d]);
            }
        }
        if (more) {
            __syncthreads();
            WRITEC();
            __syncthreads();
        }
    }
    size_t bmi = ((size_t)(s * B_ + b)) * DD * N_ + n0 + tid;
    size_t bmo = ((size_t)((NS + s) * B_ + b)) * DD * N_ + n0 + tid;
    #pragma unroll
    for (int d = 0; d < DD; d++) {
        part[bmi + (size_t)d * N_] = mi[d];
        part[bmo + (size_t)d * N_] = mo[d];
    }
}

// ---------------- node finish: reduce partials, node MLP, H = [tanh(.), X] -------
__global__ void k_node_finish(const float* __restrict__ part,
        const float* __restrict__ Wn1, const float* __restrict__ bn1,
        const float* __restrict__ Wn2, const float* __restrict__ bn2,
        float* __restrict__ H, int NS) {
    int idx = blockIdx.x * 256 + threadIdx.x;
    if (idx >= B_ * N_) return;
    int b = idx / N_, n = idx % N_;

    float mi[DD], mo[DD];
    #pragma unroll
    for (int d = 0; d < DD; d++) { mi[d] = 0.f; mo[d] = 0.f; }
    for (int s = 0; s < NS; s++) {
        size_t pmi = ((size_t)(s * B_ + b)) * DD * N_ + n;
        size_t pmo = ((size_t)((NS + s) * B_ + b)) * DD * N_ + n;
        #pragma unroll
        for (int d = 0; d < DD; d++) {
            mi[d] += part[pmi + (size_t)d * N_];
            mo[d] += part[pmo + (size_t)d * N_];
        }
    }
    float* h = H + (size_t)idx * DD;
    float hold[DD];
    #pragma unroll
    for (int d = 0; d < DD; d++) hold[d] = h[d];

    float t1[HD];
    #pragma unroll
    for (int j = 0; j < HD; j++) {
        float acc = bn1[j];
        #pragma unroll
        for (int d = 0; d < DD; d++) acc = fmaf(mi[d],   Wn1[d * HD + j], acc);
        #pragma unroll
        for (int d = 0; d < DD; d++) acc = fmaf(mo[d],   Wn1[(DD + d) * HD + j], acc);
        #pragma unroll
        for (int d = 0; d < DD; d++) acc = fmaf(hold[d], Wn1[(2 * DD + d) * HD + j], acc);
        t1[j] = tanhf(acc);
    }
    #pragma unroll
    for (int j = 0; j < HD; j++) {
        float acc = bn2[j];
        #pragma unroll
        for (int k = 0; k < HD; k++) acc = fmaf(t1[k], Wn2[k * HD + j], acc);
        h[j] = tanhf(acc);
    }
}

extern "C" void kernel_launch(void* const* d_in, const int* in_sizes, int n_in,
                              void* d_out, int out_size, void* d_ws, size_t ws_size,
                              hipStream_t stream) {
    const float* X   = (const float*)d_in[0];
    const float* Ri  = (const float*)d_in[1];
    const float* Ro  = (const float*)d_in[2];
    const float* Wi  = (const float*)d_in[3];
    const float* bi  = (const float*)d_in[4];
    const float* We1 = (const float*)d_in[5];
    const float* be1 = (const float*)d_in[6];
    const float* We2 = (const float*)d_in[7];
    const float* be2 = (const float*)d_in[8];
    const float* Wn1 = (const float*)d_in[9];
    const float* bn1 = (const float*)d_in[10];
    const float* Wn2 = (const float*)d_in[11];
    const float* bn2 = (const float*)d_in[12];
    float* out = (float*)d_out;

    const size_t H_FL  = (size_t)B_ * N_ * DD;
    const size_t WB_FL = (size_t)B_ * E_ * DD;
    auto spart_fl = [](int ns) { return 2ull * ns * B_ * DD * N_; };
    auto needT = [&](int ns) {
        return 2ull * RTOT * 2 + 4ull * (H_FL + 2 * WB_FL + spart_fl(ns));
    };

    int NS = 16;
    if (needT(NS) > ws_size) NS = 8;

    if (needT(NS) <= ws_size) {
        // ---------------- transposed-fp16 path ----------------
        char* p = (char*)d_ws;
        __half* RiT = (__half*)p;  p += RTOT * 2;
        __half* RoT = (__half*)p;  p += RTOT * 2;
        float* H    = (float*)p;   p += H_FL * 4;
        float* wbo  = (float*)p;   p += WB_FL * 4;
        float* wbi  = (float*)p;   p += WB_FL * 4;
        float* spart = (float*)p;

        k_input<<<(B_ * N_ + 255) / 256, 256, 0, stream>>>(X, Wi, bi, H);
        // iteration 0 edge fused with transpose-convert
        k_fused<<<B_ * 32, 256, 0, stream>>>(Ri, Ro, H, We1, be1, We2, be2,
                                             RiT, RoT, wbo, wbi);
        for (int it = 0; it < 3; it++) {
            k_scatter_T<<<B_ * 2 * NS, 256, 0, stream>>>(RiT, RoT, wbo, wbi, spart, NS);
            k_node_finish<<<(B_ * N_ + 255) / 256, 256, 0, stream>>>(
                spart, Wn1, bn1, Wn2, bn2, H, NS);
            k_edge_f<<<B_ * 32, 256, 0, stream>>>(Ri, Ro, H, We1, be1, We2, be2,
                                                  wbo, wbi, out, it == 2 ? 1 : 0);
        }
    } else {
        // ---------------- f32 fallback ----------------
        size_t fl = ws_size / sizeof(float);
        int NSS = 8;
        auto need = [&](int s) { return H_FL + 2 * WB_FL + spart_fl(s); };
        if (need(NSS) > fl) NSS = 4;
        if (need(NSS) > fl) NSS = 2;

        float* ws    = (float*)d_ws;
        float* H     = ws;  ws += H_FL;
        float* wbo   = ws;  ws += WB_FL;
        float* wbi   = ws;  ws += WB_FL;
        float* spart = ws;

        k_input<<<(B_ * N_ + 255) / 256, 256, 0, stream>>>(X, Wi, bi, H);
        for (int it = 0; it < 3; it++) {
            k_edge_f<<<B_ * 32, 256, 0, stream>>>(Ri, Ro, H, We1, be1, We2, be2,
                                                  wbo, wbi, out, 0);
            k_scatter_f<<<B_ * 4 * NSS, 256, 0, stream>>>(
                Ri, Ro, wbo, wbi, spart, NSS);
            k_node_finish<<<(B_ * N_ + 255) / 256, 256, 0, stream>>>(
                spart, Wn1, bn1, Wn2, bn2, H, NSS);
        }
        k_edge_f<<<B_ * 32, 256, 0, stream>>>(Ri, Ro, H, We1, be1, We2, be2,
                                              wbo, wbi, out, 1);
    }
}